// Round 10
// baseline (32.869 us; speedup 1.0000x reference)
//
#include <hip/hip_runtime.h>
#include <math.h>

constexpr int NPTS = 1024;

struct F3 { float x, y, z; };   // 12-byte point -> dense dwordx3 loads

// ---------------- Phase A: half-batch per wave (max TLP, zero sync) --------
// 2 waves per batch, 8 points per lane. 8192 independent waves; with
// __launch_bounds__(256,8) and VGPR<=64 this gives 32 waves/CU resident.
// Each wave writes its 15 partial sums to its own 64B ws slot (no sync).
__global__ __launch_bounds__(256, 8) void reduce_kernel(
    const float* __restrict__ src, const float* __restrict__ tgt,
    float* __restrict__ ws, int nbatch)
{
    const int gwave = (blockIdx.x * 256 + threadIdx.x) >> 6;
    const int lane = threadIdx.x & 63;
    const int b = gwave >> 1;          // batch
    const int h = gwave & 1;           // which half of the batch
    if (b >= nbatch) return;

    const size_t base = (size_t)b * (NPTS * 3);
    const F3* __restrict__ ps = (const F3*)(src + base);
    const F3* __restrict__ pt = (const F3*)(tgt + base);

    float acc[15];
#pragma unroll
    for (int i = 0; i < 15; ++i) acc[i] = 0.f;

#pragma unroll
    for (int k = 0; k < 8; ++k) {
        const int p = h * 512 + k * 64 + lane;
        F3 s = ps[p];
        F3 t = pt[p];
        acc[0] += s.x; acc[1] += s.y; acc[2] += s.z;
        acc[3] += t.x; acc[4] += t.y; acc[5] += t.z;
        acc[6]  += s.x * t.x; acc[7]  += s.x * t.y; acc[8]  += s.x * t.z;
        acc[9]  += s.y * t.x; acc[10] += s.y * t.y; acc[11] += s.y * t.z;
        acc[12] += s.z * t.x; acc[13] += s.z * t.y; acc[14] += s.z * t.z;
    }

    // wave butterfly reduce (valid on lane 0)
#pragma unroll
    for (int off = 32; off >= 1; off >>= 1) {
#pragma unroll
        for (int i = 0; i < 15; ++i)
            acc[i] += __shfl_down(acc[i], off, 64);
    }

    if (lane == 0) {
        float4* w = (float4*)(ws + ((size_t)b * 2 + h) * 16);
        w[0] = make_float4(acc[0],  acc[1],  acc[2],  acc[3]);
        w[1] = make_float4(acc[4],  acc[5],  acc[6],  acc[7]);
        w[2] = make_float4(acc[8],  acc[9],  acc[10], acc[11]);
        w[3] = make_float4(acc[12], acc[13], acc[14], 0.f);
    }
}

// fast HW approximations (v_rcp_f32 / v_rsq_f32 / v_sqrt_f32, ~1ulp)
__device__ __forceinline__ float frcp(float x)  { return __builtin_amdgcn_rcpf(x); }
__device__ __forceinline__ float frsq(float x)  { return __builtin_amdgcn_rsqf(x); }
__device__ __forceinline__ float fsqrt(float x) { return __builtin_amdgcn_sqrtf(x); }

// ---------------- Phase B: one 3x3 SVD per LANE (latency-bound chain) ------
__global__ __launch_bounds__(256) void svd_kernel(
    const float* __restrict__ ws, float* __restrict__ out, int nbatch)
{
    const int b = blockIdx.x * 256 + threadIdx.x;
    if (b >= nbatch) return;

    // combine the two half-batch partial sums
    const float4* w = (const float4*)(ws + (size_t)b * 32);
    float4 a0 = w[0], a1 = w[1], a2 = w[2], a3 = w[3];
    float4 b0 = w[4], b1 = w[5], b2 = w[6], b3 = w[7];
    float r[15] = {a0.x + b0.x, a0.y + b0.y, a0.z + b0.z, a0.w + b0.w,
                   a1.x + b1.x, a1.y + b1.y, a1.z + b1.z, a1.w + b1.w,
                   a2.x + b2.x, a2.y + b2.y, a2.z + b2.z, a2.w + b2.w,
                   a3.x + b3.x, a3.y + b3.y, a3.z + b3.z};

    const float invN = 1.0f / (float)NPTS;
    float mus[3] = {r[0] * invN, r[1] * invN, r[2] * invN};
    float mut[3] = {r[3] * invN, r[4] * invN, r[5] * invN};

    float H[3][3];
#pragma unroll
    for (int i = 0; i < 3; ++i)
#pragma unroll
        for (int j = 0; j < 3; ++j)
            H[i][j] = r[6 + i * 3 + j] - (float)NPTS * mus[i] * mut[j];

    // A = H^T H (symmetric PSD)
    float A[3][3];
#pragma unroll
    for (int i = 0; i < 3; ++i)
#pragma unroll
        for (int j = 0; j < 3; ++j)
            A[i][j] = H[0][i] * H[0][j] + H[1][i] * H[1][j] + H[2][i] * H[2][j];

    // cyclic Jacobi with HW-fast rcp/rsq/sqrt (short dependent chain)
    float V[3][3] = {{1.f, 0.f, 0.f}, {0.f, 1.f, 0.f}, {0.f, 0.f, 1.f}};
    auto rot = [&](int p, int q) {
        float apq = A[p][q];
        float diff = A[q][q] - A[p][p];
        float theta = diff * frcp(2.0f * apq);
        float t = copysignf(frcp(fabsf(theta) + fsqrt(fmaf(theta, theta, 1.0f))), theta);
        t = (fabsf(apq) < 1e-20f) ? 0.0f : t;   // apq==0 -> identity rotation
        float c = frsq(fmaf(t, t, 1.0f));
        float s = t * c;
#pragma unroll
        for (int k = 0; k < 3; ++k) {
            float akp = A[k][p], akq = A[k][q];
            A[k][p] = c * akp - s * akq;
            A[k][q] = s * akp + c * akq;
        }
#pragma unroll
        for (int k = 0; k < 3; ++k) {
            float apk = A[p][k], aqk = A[q][k];
            A[p][k] = c * apk - s * aqk;
            A[q][k] = s * apk + c * aqk;
        }
#pragma unroll
        for (int k = 0; k < 3; ++k) {
            float vkp = V[k][p], vkq = V[k][q];
            V[k][p] = c * vkp - s * vkq;
            V[k][q] = s * vkp + c * vkq;
        }
    };
#pragma unroll
    for (int sweep = 0; sweep < 4; ++sweep) {
        rot(0, 1);
        rot(0, 2);
        rot(1, 2);
    }

    // branchless descending sort of eigenpairs
    float l0 = A[0][0], l1 = A[1][1], l2 = A[2][2];
    float e0[3] = {V[0][0], V[1][0], V[2][0]};
    float e1[3] = {V[0][1], V[1][1], V[2][1]};
    float e2[3] = {V[0][2], V[1][2], V[2][2]};
    auto cswap = [](float& la, float* va, float& lb, float* vb) {
        bool sw = lb > la;
        float tl = sw ? lb : la;
        lb = sw ? la : lb;
        la = tl;
#pragma unroll
        for (int k = 0; k < 3; ++k) {
            float tv2 = sw ? vb[k] : va[k];
            vb[k] = sw ? va[k] : vb[k];
            va[k] = tv2;
        }
    };
    cswap(l0, e0, l1, e1);
    cswap(l0, e0, l2, e2);
    cswap(l1, e1, l2, e2);

    float *v1 = e0, *v2 = e1, *v3 = e2;

    // u1 = norm(H v1); u2 = GramSchmidt(H v2); u3 = u1 x u2  (det U = +1)
    float u1[3], u2[3], u3[3], hv[3];
    hv[0] = H[0][0]*v1[0] + H[0][1]*v1[1] + H[0][2]*v1[2];
    hv[1] = H[1][0]*v1[0] + H[1][1]*v1[1] + H[1][2]*v1[2];
    hv[2] = H[2][0]*v1[0] + H[2][1]*v1[1] + H[2][2]*v1[2];
    {
        float n = frsq(fmaf(hv[0], hv[0], fmaf(hv[1], hv[1], hv[2]*hv[2])) + 1e-30f);
        u1[0] = hv[0] * n; u1[1] = hv[1] * n; u1[2] = hv[2] * n;
    }
    hv[0] = H[0][0]*v2[0] + H[0][1]*v2[1] + H[0][2]*v2[2];
    hv[1] = H[1][0]*v2[0] + H[1][1]*v2[1] + H[1][2]*v2[2];
    hv[2] = H[2][0]*v2[0] + H[2][1]*v2[1] + H[2][2]*v2[2];
    {
        float d = u1[0]*hv[0] + u1[1]*hv[1] + u1[2]*hv[2];
        hv[0] -= d * u1[0]; hv[1] -= d * u1[1]; hv[2] -= d * u1[2];
        float n = frsq(fmaf(hv[0], hv[0], fmaf(hv[1], hv[1], hv[2]*hv[2])) + 1e-30f);
        u2[0] = hv[0] * n; u2[1] = hv[1] * n; u2[2] = hv[2] * n;
    }
    u3[0] = u1[1]*u2[2] - u1[2]*u2[1];
    u3[1] = u1[2]*u2[0] - u1[0]*u2[2];
    u3[2] = u1[0]*u2[1] - u1[1]*u2[0];

    // R = v1 u1^T + v2 u2^T + det(V) * v3 u3^T
    float cx = v1[1]*v2[2] - v1[2]*v2[1];
    float cy = v1[2]*v2[0] - v1[0]*v2[2];
    float cz = v1[0]*v2[1] - v1[1]*v2[0];
    float detV = cx * v3[0] + cy * v3[1] + cz * v3[2];
    float d3 = (detV < 0.f) ? -1.f : 1.f;

    float R[3][3];
#pragma unroll
    for (int i = 0; i < 3; ++i)
#pragma unroll
        for (int j = 0; j < 3; ++j)
            R[i][j] = v1[i]*u1[j] + v2[i]*u2[j] + d3 * v3[i]*u3[j];

    float tvec[3];
#pragma unroll
    for (int i = 0; i < 3; ++i)
        tvec[i] = mut[i] - (R[i][0]*mus[0] + R[i][1]*mus[1] + R[i][2]*mus[2]);

    float* Rout = out + (size_t)b * 9;
#pragma unroll
    for (int i = 0; i < 3; ++i)
#pragma unroll
        for (int j = 0; j < 3; ++j)
            Rout[i * 3 + j] = R[i][j];
    float* tout = out + (size_t)nbatch * 9 + (size_t)b * 3;
#pragma unroll
    for (int i = 0; i < 3; ++i) tout[i] = tvec[i];
}

extern "C" void kernel_launch(void* const* d_in, const int* in_sizes, int n_in,
                              void* d_out, int out_size, void* d_ws, size_t ws_size,
                              hipStream_t stream) {
    const float* src = (const float*)d_in[0];
    const float* tgt = (const float*)d_in[1];
    float* out = (float*)d_out;
    float* ws = (float*)d_ws;
    const int nbatch = in_sizes[0] / (NPTS * 3);

    const int nwaves = nbatch * 2;                 // 2 waves per batch
    const int nblocksA = (nwaves + 3) / 4;         // 4 waves per block
    reduce_kernel<<<nblocksA, 256, 0, stream>>>(src, tgt, ws, nbatch);

    const int nblocksB = (nbatch + 255) / 256;
    svd_kernel<<<nblocksB, 256, 0, stream>>>(ws, out, nbatch);
}

// Round 11
// 24.789 us; speedup vs baseline: 1.3259x; 1.3259x over previous
//
#include <hip/hip_runtime.h>
#include <math.h>

constexpr int NPTS = 1024;
constexpr int WPB = 2;   // waves (= batches) per 128-thread block, phase A

struct F3 { float x, y, z; };   // 12-byte point -> dense dwordx3 loads

// ---------------- Phase A: per-batch 15-sum reduction (memory-bound) -------
// 128-thread blocks double the resident-block count per CU vs 256-thread
// blocks at the same VGPR budget -> ~2x outstanding loads per CU.
__global__ void reduce_kernel(
    const float* __restrict__ src, const float* __restrict__ tgt,
    float* __restrict__ ws, int nbatch)
{
    const int wave = threadIdx.x >> 6;
    const int lane = threadIdx.x & 63;
    const int b = blockIdx.x * WPB + wave;
    if (b >= nbatch) return;

    const size_t base = (size_t)b * (NPTS * 3);
    const F3* __restrict__ ps = (const F3*)(src + base);
    const F3* __restrict__ pt = (const F3*)(tgt + base);

    float acc[15];
#pragma unroll
    for (int i = 0; i < 15; ++i) acc[i] = 0.f;

#pragma unroll
    for (int k = 0; k < 16; ++k) {
        const int p = k * 64 + lane;
        F3 s = ps[p];
        F3 t = pt[p];
        acc[0] += s.x; acc[1] += s.y; acc[2] += s.z;
        acc[3] += t.x; acc[4] += t.y; acc[5] += t.z;
        acc[6]  += s.x * t.x; acc[7]  += s.x * t.y; acc[8]  += s.x * t.z;
        acc[9]  += s.y * t.x; acc[10] += s.y * t.y; acc[11] += s.y * t.z;
        acc[12] += s.z * t.x; acc[13] += s.z * t.y; acc[14] += s.z * t.z;
    }

    // wave butterfly reduce (valid on lane 0)
#pragma unroll
    for (int off = 32; off >= 1; off >>= 1) {
#pragma unroll
        for (int i = 0; i < 15; ++i)
            acc[i] += __shfl_down(acc[i], off, 64);
    }

    if (lane == 0) {
        float4* w = (float4*)(ws + (size_t)b * 16);
        w[0] = make_float4(acc[0],  acc[1],  acc[2],  acc[3]);
        w[1] = make_float4(acc[4],  acc[5],  acc[6],  acc[7]);
        w[2] = make_float4(acc[8],  acc[9],  acc[10], acc[11]);
        w[3] = make_float4(acc[12], acc[13], acc[14], 0.f);
    }
}

// fast HW approximations (v_rcp_f32 / v_rsq_f32 / v_sqrt_f32, ~1ulp)
__device__ __forceinline__ float frcp(float x)  { return __builtin_amdgcn_rcpf(x); }
__device__ __forceinline__ float frsq(float x)  { return __builtin_amdgcn_rsqf(x); }
__device__ __forceinline__ float fsqrt(float x) { return __builtin_amdgcn_sqrtf(x); }

// ---------------- Phase B: one 3x3 SVD per LANE (latency-bound chain) ------
__global__ __launch_bounds__(256) void svd_kernel(
    const float* __restrict__ ws, float* __restrict__ out, int nbatch)
{
    const int b = blockIdx.x * 256 + threadIdx.x;
    if (b >= nbatch) return;

    const float4* w = (const float4*)(ws + (size_t)b * 16);
    float4 w0 = w[0], w1 = w[1], w2 = w[2], w3 = w[3];
    float r[15] = {w0.x, w0.y, w0.z, w0.w,
                   w1.x, w1.y, w1.z, w1.w,
                   w2.x, w2.y, w2.z, w2.w,
                   w3.x, w3.y, w3.z};

    const float invN = 1.0f / (float)NPTS;
    float mus[3] = {r[0] * invN, r[1] * invN, r[2] * invN};
    float mut[3] = {r[3] * invN, r[4] * invN, r[5] * invN};

    float H[3][3];
#pragma unroll
    for (int i = 0; i < 3; ++i)
#pragma unroll
        for (int j = 0; j < 3; ++j)
            H[i][j] = r[6 + i * 3 + j] - (float)NPTS * mus[i] * mut[j];

    // A = H^T H (symmetric PSD)
    float A[3][3];
#pragma unroll
    for (int i = 0; i < 3; ++i)
#pragma unroll
        for (int j = 0; j < 3; ++j)
            A[i][j] = H[0][i] * H[0][j] + H[1][i] * H[1][j] + H[2][i] * H[2][j];

    // cyclic Jacobi with HW-fast rcp/rsq/sqrt (short dependent chain)
    float V[3][3] = {{1.f, 0.f, 0.f}, {0.f, 1.f, 0.f}, {0.f, 0.f, 1.f}};
    auto rot = [&](int p, int q) {
        float apq = A[p][q];
        float diff = A[q][q] - A[p][p];
        float theta = diff * frcp(2.0f * apq);
        float t = copysignf(frcp(fabsf(theta) + fsqrt(fmaf(theta, theta, 1.0f))), theta);
        t = (fabsf(apq) < 1e-20f) ? 0.0f : t;   // apq==0 -> identity rotation
        float c = frsq(fmaf(t, t, 1.0f));
        float s = t * c;
#pragma unroll
        for (int k = 0; k < 3; ++k) {
            float akp = A[k][p], akq = A[k][q];
            A[k][p] = c * akp - s * akq;
            A[k][q] = s * akp + c * akq;
        }
#pragma unroll
        for (int k = 0; k < 3; ++k) {
            float apk = A[p][k], aqk = A[q][k];
            A[p][k] = c * apk - s * aqk;
            A[q][k] = s * apk + c * aqk;
        }
#pragma unroll
        for (int k = 0; k < 3; ++k) {
            float vkp = V[k][p], vkq = V[k][q];
            V[k][p] = c * vkp - s * vkq;
            V[k][q] = s * vkp + c * vkq;
        }
    };
#pragma unroll
    for (int sweep = 0; sweep < 4; ++sweep) {
        rot(0, 1);
        rot(0, 2);
        rot(1, 2);
    }

    // branchless descending sort of eigenpairs
    float l0 = A[0][0], l1 = A[1][1], l2 = A[2][2];
    float e0[3] = {V[0][0], V[1][0], V[2][0]};
    float e1[3] = {V[0][1], V[1][1], V[2][1]};
    float e2[3] = {V[0][2], V[1][2], V[2][2]};
    auto cswap = [](float& la, float* va, float& lb, float* vb) {
        bool sw = lb > la;
        float tl = sw ? lb : la;
        lb = sw ? la : lb;
        la = tl;
#pragma unroll
        for (int k = 0; k < 3; ++k) {
            float tv2 = sw ? vb[k] : va[k];
            vb[k] = sw ? va[k] : vb[k];
            va[k] = tv2;
        }
    };
    cswap(l0, e0, l1, e1);
    cswap(l0, e0, l2, e2);
    cswap(l1, e1, l2, e2);

    float *v1 = e0, *v2 = e1, *v3 = e2;

    // u1 = norm(H v1); u2 = GramSchmidt(H v2); u3 = u1 x u2  (det U = +1)
    float u1[3], u2[3], u3[3], hv[3];
    hv[0] = H[0][0]*v1[0] + H[0][1]*v1[1] + H[0][2]*v1[2];
    hv[1] = H[1][0]*v1[0] + H[1][1]*v1[1] + H[1][2]*v1[2];
    hv[2] = H[2][0]*v1[0] + H[2][1]*v1[1] + H[2][2]*v1[2];
    {
        float n = frsq(fmaf(hv[0], hv[0], fmaf(hv[1], hv[1], hv[2]*hv[2])) + 1e-30f);
        u1[0] = hv[0] * n; u1[1] = hv[1] * n; u1[2] = hv[2] * n;
    }
    hv[0] = H[0][0]*v2[0] + H[0][1]*v2[1] + H[0][2]*v2[2];
    hv[1] = H[1][0]*v2[0] + H[1][1]*v2[1] + H[1][2]*v2[2];
    hv[2] = H[2][0]*v2[0] + H[2][1]*v2[1] + H[2][2]*v2[2];
    {
        float d = u1[0]*hv[0] + u1[1]*hv[1] + u1[2]*hv[2];
        hv[0] -= d * u1[0]; hv[1] -= d * u1[1]; hv[2] -= d * u1[2];
        float n = frsq(fmaf(hv[0], hv[0], fmaf(hv[1], hv[1], hv[2]*hv[2])) + 1e-30f);
        u2[0] = hv[0] * n; u2[1] = hv[1] * n; u2[2] = hv[2] * n;
    }
    u3[0] = u1[1]*u2[2] - u1[2]*u2[1];
    u3[1] = u1[2]*u2[0] - u1[0]*u2[2];
    u3[2] = u1[0]*u2[1] - u1[1]*u2[0];

    // R = v1 u1^T + v2 u2^T + det(V) * v3 u3^T
    float cx = v1[1]*v2[2] - v1[2]*v2[1];
    float cy = v1[2]*v2[0] - v1[0]*v2[2];
    float cz = v1[0]*v2[1] - v1[1]*v2[0];
    float detV = cx * v3[0] + cy * v3[1] + cz * v3[2];
    float d3 = (detV < 0.f) ? -1.f : 1.f;

    float R[3][3];
#pragma unroll
    for (int i = 0; i < 3; ++i)
#pragma unroll
        for (int j = 0; j < 3; ++j)
            R[i][j] = v1[i]*u1[j] + v2[i]*u2[j] + d3 * v3[i]*u3[j];

    float tvec[3];
#pragma unroll
    for (int i = 0; i < 3; ++i)
        tvec[i] = mut[i] - (R[i][0]*mus[0] + R[i][1]*mus[1] + R[i][2]*mus[2]);

    float* Rout = out + (size_t)b * 9;
#pragma unroll
    for (int i = 0; i < 3; ++i)
#pragma unroll
        for (int j = 0; j < 3; ++j)
            Rout[i * 3 + j] = R[i][j];
    float* tout = out + (size_t)nbatch * 9 + (size_t)b * 3;
#pragma unroll
    for (int i = 0; i < 3; ++i) tout[i] = tvec[i];
}

extern "C" void kernel_launch(void* const* d_in, const int* in_sizes, int n_in,
                              void* d_out, int out_size, void* d_ws, size_t ws_size,
                              hipStream_t stream) {
    const float* src = (const float*)d_in[0];
    const float* tgt = (const float*)d_in[1];
    float* out = (float*)d_out;
    float* ws = (float*)d_ws;
    const int nbatch = in_sizes[0] / (NPTS * 3);

    const int nblocksA = (nbatch + WPB - 1) / WPB;
    reduce_kernel<<<nblocksA, WPB * 64, 0, stream>>>(src, tgt, ws, nbatch);

    const int nblocksB = (nbatch + 255) / 256;
    svd_kernel<<<nblocksB, 256, 0, stream>>>(ws, out, nbatch);
}

// Round 12
// 24.429 us; speedup vs baseline: 1.3455x; 1.0147x over previous
//
#include <hip/hip_runtime.h>
#include <math.h>

constexpr int NPTS = 1024;
constexpr int WPB = 4;   // waves (= batches) per block, phase A

struct F3 { float x, y, z; };   // 12-byte point -> dense dwordx3 loads

// ---------------- Phase A: per-batch 15-sum reduction (memory-bound) -------
// Wave owns one batch; lane loads point (k*64+lane) as a dense 12B dwordx3.
// Reduction: 2 shuffle stages (64->16 lanes) + conflict-free LDS transpose
// ([16][17] pad), then lanes 0..14 each finish one sum and store it.
__global__ __launch_bounds__(256, 4) void reduce_kernel(
    const float* __restrict__ src, const float* __restrict__ tgt,
    float* __restrict__ ws, int nbatch)
{
    const int wave = threadIdx.x >> 6;
    const int lane = threadIdx.x & 63;
    const int b = blockIdx.x * WPB + wave;
    if (b >= nbatch) return;

    const size_t base = (size_t)b * (NPTS * 3);
    const F3* __restrict__ ps = (const F3*)(src + base);
    const F3* __restrict__ pt = (const F3*)(tgt + base);

    float acc[15];
#pragma unroll
    for (int i = 0; i < 15; ++i) acc[i] = 0.f;

#pragma unroll
    for (int k = 0; k < 16; ++k) {
        const int p = k * 64 + lane;
        F3 s = ps[p];
        F3 t = pt[p];
        acc[0] += s.x; acc[1] += s.y; acc[2] += s.z;
        acc[3] += t.x; acc[4] += t.y; acc[5] += t.z;
        acc[6]  += s.x * t.x; acc[7]  += s.x * t.y; acc[8]  += s.x * t.z;
        acc[9]  += s.y * t.x; acc[10] += s.y * t.y; acc[11] += s.y * t.z;
        acc[12] += s.z * t.x; acc[13] += s.z * t.y; acc[14] += s.z * t.z;
    }

    // 2 butterfly stages: partials valid in lanes 0..15
#pragma unroll
    for (int off = 32; off >= 16; off >>= 1) {
#pragma unroll
        for (int i = 0; i < 15; ++i)
            acc[i] += __shfl_down(acc[i], off, 64);
    }

    // LDS transpose (pad 17 -> conflict-free rows and columns), same wave:
    // compiler orders ds_write -> ds_read via lgkmcnt, no barrier needed.
    __shared__ float xp[WPB][16][17];
    if (lane < 16) {
#pragma unroll
        for (int i = 0; i < 15; ++i) xp[wave][lane][i] = acc[i];
    }
    if (lane < 15) {
        float sum = 0.f;
#pragma unroll
        for (int l = 0; l < 16; ++l) sum += xp[wave][l][lane];
        ws[(size_t)b * 16 + lane] = sum;   // 15 parallel dword stores
    }
}

// fast HW approximations (v_rcp_f32 / v_rsq_f32 / v_sqrt_f32, ~1ulp)
__device__ __forceinline__ float frcp(float x)  { return __builtin_amdgcn_rcpf(x); }
__device__ __forceinline__ float frsq(float x)  { return __builtin_amdgcn_rsqf(x); }
__device__ __forceinline__ float fsqrt(float x) { return __builtin_amdgcn_sqrtf(x); }

// ---------------- Phase B: one 3x3 SVD per LANE (latency-bound chain) ------
__global__ __launch_bounds__(256) void svd_kernel(
    const float* __restrict__ ws, float* __restrict__ out, int nbatch)
{
    const int b = blockIdx.x * 256 + threadIdx.x;
    if (b >= nbatch) return;

    const float4* w = (const float4*)(ws + (size_t)b * 16);
    float4 w0 = w[0], w1 = w[1], w2 = w[2], w3 = w[3];
    float r[15] = {w0.x, w0.y, w0.z, w0.w,
                   w1.x, w1.y, w1.z, w1.w,
                   w2.x, w2.y, w2.z, w2.w,
                   w3.x, w3.y, w3.z};

    const float invN = 1.0f / (float)NPTS;
    float mus[3] = {r[0] * invN, r[1] * invN, r[2] * invN};
    float mut[3] = {r[3] * invN, r[4] * invN, r[5] * invN};

    float H[3][3];
#pragma unroll
    for (int i = 0; i < 3; ++i)
#pragma unroll
        for (int j = 0; j < 3; ++j)
            H[i][j] = r[6 + i * 3 + j] - (float)NPTS * mus[i] * mut[j];

    // A = H^T H (symmetric PSD)
    float A[3][3];
#pragma unroll
    for (int i = 0; i < 3; ++i)
#pragma unroll
        for (int j = 0; j < 3; ++j)
            A[i][j] = H[0][i] * H[0][j] + H[1][i] * H[1][j] + H[2][i] * H[2][j];

    // cyclic Jacobi with HW-fast rcp/rsq/sqrt (short dependent chain)
    float V[3][3] = {{1.f, 0.f, 0.f}, {0.f, 1.f, 0.f}, {0.f, 0.f, 1.f}};
    auto rot = [&](int p, int q) {
        float apq = A[p][q];
        float diff = A[q][q] - A[p][p];
        float theta = diff * frcp(2.0f * apq);
        float t = copysignf(frcp(fabsf(theta) + fsqrt(fmaf(theta, theta, 1.0f))), theta);
        t = (fabsf(apq) < 1e-20f) ? 0.0f : t;   // apq==0 -> identity rotation
        float c = frsq(fmaf(t, t, 1.0f));
        float s = t * c;
#pragma unroll
        for (int k = 0; k < 3; ++k) {
            float akp = A[k][p], akq = A[k][q];
            A[k][p] = c * akp - s * akq;
            A[k][q] = s * akp + c * akq;
        }
#pragma unroll
        for (int k = 0; k < 3; ++k) {
            float apk = A[p][k], aqk = A[q][k];
            A[p][k] = c * apk - s * aqk;
            A[q][k] = s * apk + c * aqk;
        }
#pragma unroll
        for (int k = 0; k < 3; ++k) {
            float vkp = V[k][p], vkq = V[k][q];
            V[k][p] = c * vkp - s * vkq;
            V[k][q] = s * vkp + c * vkq;
        }
    };
#pragma unroll
    for (int sweep = 0; sweep < 4; ++sweep) {
        rot(0, 1);
        rot(0, 2);
        rot(1, 2);
    }

    // branchless descending sort of eigenpairs
    float l0 = A[0][0], l1 = A[1][1], l2 = A[2][2];
    float e0[3] = {V[0][0], V[1][0], V[2][0]};
    float e1[3] = {V[0][1], V[1][1], V[2][1]};
    float e2[3] = {V[0][2], V[1][2], V[2][2]};
    auto cswap = [](float& la, float* va, float& lb, float* vb) {
        bool sw = lb > la;
        float tl = sw ? lb : la;
        lb = sw ? la : lb;
        la = tl;
#pragma unroll
        for (int k = 0; k < 3; ++k) {
            float tv2 = sw ? vb[k] : va[k];
            vb[k] = sw ? va[k] : vb[k];
            va[k] = tv2;
        }
    };
    cswap(l0, e0, l1, e1);
    cswap(l0, e0, l2, e2);
    cswap(l1, e1, l2, e2);

    float *v1 = e0, *v2 = e1, *v3 = e2;

    // u1 = norm(H v1); u2 = GramSchmidt(H v2); u3 = u1 x u2  (det U = +1)
    float u1[3], u2[3], u3[3], hv[3];
    hv[0] = H[0][0]*v1[0] + H[0][1]*v1[1] + H[0][2]*v1[2];
    hv[1] = H[1][0]*v1[0] + H[1][1]*v1[1] + H[1][2]*v1[2];
    hv[2] = H[2][0]*v1[0] + H[2][1]*v1[1] + H[2][2]*v1[2];
    {
        float n = frsq(fmaf(hv[0], hv[0], fmaf(hv[1], hv[1], hv[2]*hv[2])) + 1e-30f);
        u1[0] = hv[0] * n; u1[1] = hv[1] * n; u1[2] = hv[2] * n;
    }
    hv[0] = H[0][0]*v2[0] + H[0][1]*v2[1] + H[0][2]*v2[2];
    hv[1] = H[1][0]*v2[0] + H[1][1]*v2[1] + H[1][2]*v2[2];
    hv[2] = H[2][0]*v2[0] + H[2][1]*v2[1] + H[2][2]*v2[2];
    {
        float d = u1[0]*hv[0] + u1[1]*hv[1] + u1[2]*hv[2];
        hv[0] -= d * u1[0]; hv[1] -= d * u1[1]; hv[2] -= d * u1[2];
        float n = frsq(fmaf(hv[0], hv[0], fmaf(hv[1], hv[1], hv[2]*hv[2])) + 1e-30f);
        u2[0] = hv[0] * n; u2[1] = hv[1] * n; u2[2] = hv[2] * n;
    }
    u3[0] = u1[1]*u2[2] - u1[2]*u2[1];
    u3[1] = u1[2]*u2[0] - u1[0]*u2[2];
    u3[2] = u1[0]*u2[1] - u1[1]*u2[0];

    // R = v1 u1^T + v2 u2^T + det(V) * v3 u3^T
    float cx = v1[1]*v2[2] - v1[2]*v2[1];
    float cy = v1[2]*v2[0] - v1[0]*v2[2];
    float cz = v1[0]*v2[1] - v1[1]*v2[0];
    float detV = cx * v3[0] + cy * v3[1] + cz * v3[2];
    float d3 = (detV < 0.f) ? -1.f : 1.f;

    float R[3][3];
#pragma unroll
    for (int i = 0; i < 3; ++i)
#pragma unroll
        for (int j = 0; j < 3; ++j)
            R[i][j] = v1[i]*u1[j] + v2[i]*u2[j] + d3 * v3[i]*u3[j];

    float tvec[3];
#pragma unroll
    for (int i = 0; i < 3; ++i)
        tvec[i] = mut[i] - (R[i][0]*mus[0] + R[i][1]*mus[1] + R[i][2]*mus[2]);

    float* Rout = out + (size_t)b * 9;
#pragma unroll
    for (int i = 0; i < 3; ++i)
#pragma unroll
        for (int j = 0; j < 3; ++j)
            Rout[i * 3 + j] = R[i][j];
    float* tout = out + (size_t)nbatch * 9 + (size_t)b * 3;
#pragma unroll
    for (int i = 0; i < 3; ++i) tout[i] = tvec[i];
}

extern "C" void kernel_launch(void* const* d_in, const int* in_sizes, int n_in,
                              void* d_out, int out_size, void* d_ws, size_t ws_size,
                              hipStream_t stream) {
    const float* src = (const float*)d_in[0];
    const float* tgt = (const float*)d_in[1];
    float* out = (float*)d_out;
    float* ws = (float*)d_ws;
    const int nbatch = in_sizes[0] / (NPTS * 3);

    const int nblocksA = (nbatch + WPB - 1) / WPB;
    reduce_kernel<<<nblocksA, 256, 0, stream>>>(src, tgt, ws, nbatch);

    const int nblocksB = (nbatch + 255) / 256;
    svd_kernel<<<nblocksB, 256, 0, stream>>>(ws, out, nbatch);
}